// Round 4
// baseline (837.066 us; speedup 1.0000x reference)
//
#include <hip/hip_runtime.h>
#include <hip/hip_cooperative_groups.h>
#include <math.h>

namespace cg = cooperative_groups;

// SCQ layer forward.
//   dense+LN f32 (argmin-critical Z bits).
//   small-matrix chain (S, Newton-Schulz Sinv, Ut, Ainv, diversity) in ONE
//   cooperative kernel with grid.sync between phases.
//   score: split-bf16 MFMA approx dists + per-row top-2; rows with gap < TAU
//   repaired by bit-exact f32 rescoring (same fmaf order as round 3).
//   post-argmin GEMMs (P_sol, Zq) split-bf16 x3 MFMA.

#define M_ 32768
#define D_ 256
#define K_ 512
#define TAU 0.02f

typedef short bf16x8 __attribute__((ext_vector_type(8)));
typedef unsigned short u16x8 __attribute__((ext_vector_type(8)));
typedef float f32x4 __attribute__((ext_vector_type(4)));

#define LSTR 56   // LDS row stride (ushorts)

// split 16 consecutive f32 into bf16 hi/lo planes (truncation split)
__device__ inline void stage16(const float* __restrict__ g,
                               unsigned short* __restrict__ lh,
                               unsigned short* __restrict__ ll)
{
    unsigned short hi[16], lo[16];
#pragma unroll
    for (int q = 0; q < 4; ++q) {
        float4 v = ((const float4*)g)[q];
        float f[4] = {v.x, v.y, v.z, v.w};
#pragma unroll
        for (int e = 0; e < 4; ++e) {
            unsigned int u = __float_as_uint(f[e]);
            unsigned short h = (unsigned short)(u >> 16);
            float fh = __uint_as_float(((unsigned int)h) << 16);
            float r = f[e] - fh;
            unsigned short l = (unsigned short)(__float_as_uint(r) >> 16);
            hi[q*4+e] = h; lo[q*4+e] = l;
        }
    }
    *(u16x8*)lh       = *(u16x8*)hi;
    *(u16x8*)(lh + 8) = *(u16x8*)(hi + 8);
    *(u16x8*)ll       = *(u16x8*)lo;
    *(u16x8*)(ll + 8) = *(u16x8*)(lo + 8);
}

// ---- MFMA GEMM: Out(MxN) = A(MxKd) @ Bt^T, Bt is (N x Kd) row-major --------
// EPI: 2 = +Ainv[assign[row],col] (psol, N=512); 3 = Zq + loss partials (N=256)
template<int EPI>
__global__ __launch_bounds__(256)
void mfma_gemm(const float* __restrict__ A, const float* __restrict__ Bt,
               float* __restrict__ Out, int Kd, int N,
               const float* __restrict__ AinvM, const int* __restrict__ assign,
               const float* Zref, float* __restrict__ lossPart)
{
    __shared__ unsigned short sAh[128*LSTR], sAl[128*LSTR];
    __shared__ unsigned short sBh[128*LSTR], sBl[128*LSTR];
    __shared__ float red[256];
    const int tid = threadIdx.x;
    const int m0 = blockIdx.y * 128, n0 = blockIdx.x * 128;
    const int w = tid >> 6, lane = tid & 63;
    const int wr = (w & 1) * 64, wc = (w >> 1) * 64;
    const int cg = lane >> 4, cr = lane & 15;

    f32x4 acc[4][4];
    const f32x4 z4 = {0.f, 0.f, 0.f, 0.f};
#pragma unroll
    for (int i = 0; i < 4; ++i)
#pragma unroll
        for (int j = 0; j < 4; ++j) acc[i][j] = z4;

    const int sr = tid >> 1;
    const int sk = (tid & 1) * 16;
    const float* Ag = A  + (size_t)(m0 + sr) * Kd + sk;
    const float* Bg = Bt + (size_t)(n0 + sr) * Kd + sk;
    const int soff = sr * LSTR + sk;

    for (int kb = 0; kb < Kd; kb += 32) {
        stage16(Ag + kb, sAh + soff, sAl + soff);
        stage16(Bg + kb, sBh + soff, sBl + soff);
        __syncthreads();
        bf16x8 ah[4], al[4], bh[4], bl[4];
#pragma unroll
        for (int f = 0; f < 4; ++f) {
            const int ao = (wr + f*16 + cr) * LSTR + cg*8;
            ah[f] = *(const bf16x8*)&sAh[ao];
            al[f] = *(const bf16x8*)&sAl[ao];
            const int bo = (wc + f*16 + cr) * LSTR + cg*8;
            bh[f] = *(const bf16x8*)&sBh[bo];
            bl[f] = *(const bf16x8*)&sBl[bo];
        }
#pragma unroll
        for (int i = 0; i < 4; ++i)
#pragma unroll
            for (int j = 0; j < 4; ++j) {
                acc[i][j] = __builtin_amdgcn_mfma_f32_16x16x32_bf16(ah[i], bh[j], acc[i][j], 0, 0, 0);
                acc[i][j] = __builtin_amdgcn_mfma_f32_16x16x32_bf16(al[i], bh[j], acc[i][j], 0, 0, 0);
                acc[i][j] = __builtin_amdgcn_mfma_f32_16x16x32_bf16(ah[i], bl[j], acc[i][j], 0, 0, 0);
            }
        __syncthreads();
    }

    if (EPI == 2) {
#pragma unroll
        for (int i = 0; i < 4; ++i) {
#pragma unroll
            for (int q = 0; q < 4; ++q) {
                const int row = m0 + wr + i*16 + cg*4 + q;
                const int am = assign[row];
                const float* Arow = AinvM + (size_t)am * K_ + n0 + wc;
#pragma unroll
                for (int j = 0; j < 4; ++j)
                    Out[(size_t)row * N + n0 + wc + j*16 + cr] =
                        acc[i][j][q] + Arow[j*16 + cr];
            }
        }
    } else {
        float lsum = 0.f;
#pragma unroll
        for (int i = 0; i < 4; ++i) {
#pragma unroll
            for (int q = 0; q < 4; ++q) {
                const int row = m0 + wr + i*16 + cg*4 + q;
#pragma unroll
                for (int j = 0; j < 4; ++j) {
                    const int col = n0 + wc + j*16 + cr;
                    const float v = acc[i][j][q];
                    const float zv = Zref[(size_t)row * N + col];
                    const float d = v - zv;
                    lsum += d * d;
                    Out[(size_t)row * N + col] = v;
                }
            }
        }
        red[tid] = lsum;
        __syncthreads();
        for (int s = 128; s > 0; s >>= 1) {
            if (tid < s) red[tid] += red[tid + s];
            __syncthreads();
        }
        if (tid == 0) lossPart[blockIdx.y * gridDim.x + blockIdx.x] = red[0];
    }
}

// -------- score: split-bf16 MFMA dists + per-row per-stripe top-2 -----------
__global__ __launch_bounds__(256)
void score_mfma_argmin(const float* __restrict__ A, const float* __restrict__ Bt,
                       const float* __restrict__ cn2, const float* __restrict__ zn2,
                       float* __restrict__ PV, float* __restrict__ PB,
                       int* __restrict__ PI)
{
    __shared__ unsigned short sAh[128*LSTR], sAl[128*LSTR];
    __shared__ unsigned short sBh[128*LSTR], sBl[128*LSTR];
    __shared__ float l1v[128][2], l2v[128][2];
    __shared__ int   liv[128][2];
    const int tid = threadIdx.x;
    const int m0 = blockIdx.y * 128, n0 = blockIdx.x * 128;
    const int w = tid >> 6, lane = tid & 63;
    const int wr = (w & 1) * 64, wc = (w >> 1) * 64;
    const int cg = lane >> 4, cr = lane & 15;

    f32x4 acc[4][4];
    const f32x4 z4 = {0.f, 0.f, 0.f, 0.f};
#pragma unroll
    for (int i = 0; i < 4; ++i)
#pragma unroll
        for (int j = 0; j < 4; ++j) acc[i][j] = z4;

    const int sr = tid >> 1;
    const int sk = (tid & 1) * 16;
    const float* Ag = A  + (size_t)(m0 + sr) * D_ + sk;
    const float* Bg = Bt + (size_t)(n0 + sr) * D_ + sk;
    const int soff = sr * LSTR + sk;

    for (int kb = 0; kb < D_; kb += 32) {
        stage16(Ag + kb, sAh + soff, sAl + soff);
        stage16(Bg + kb, sBh + soff, sBl + soff);
        __syncthreads();
        bf16x8 ah[4], al[4], bh[4], bl[4];
#pragma unroll
        for (int f = 0; f < 4; ++f) {
            const int ao = (wr + f*16 + cr) * LSTR + cg*8;
            ah[f] = *(const bf16x8*)&sAh[ao];
            al[f] = *(const bf16x8*)&sAl[ao];
            const int bo = (wc + f*16 + cr) * LSTR + cg*8;
            bh[f] = *(const bf16x8*)&sBh[bo];
            bl[f] = *(const bf16x8*)&sBl[bo];
        }
#pragma unroll
        for (int i = 0; i < 4; ++i)
#pragma unroll
            for (int j = 0; j < 4; ++j) {
                acc[i][j] = __builtin_amdgcn_mfma_f32_16x16x32_bf16(ah[i], bh[j], acc[i][j], 0, 0, 0);
                acc[i][j] = __builtin_amdgcn_mfma_f32_16x16x32_bf16(al[i], bh[j], acc[i][j], 0, 0, 0);
                acc[i][j] = __builtin_amdgcn_mfma_f32_16x16x32_bf16(ah[i], bl[j], acc[i][j], 0, 0, 0);
            }
        __syncthreads();
    }

    const int half = wc >> 6;
#pragma unroll
    for (int i = 0; i < 4; ++i) {
#pragma unroll
        for (int q = 0; q < 4; ++q) {
            const int rl = wr + i*16 + cg*4 + q;
            const float zr = zn2[m0 + rl];
            float b1 = 3.4e38f, b2 = 3.4e38f; int i1 = 0x7fffffff;
#pragma unroll
            for (int j = 0; j < 4; ++j) {
                const int col = n0 + wc + j*16 + cr;
                const float d = (zr + cn2[col]) - 2.0f * acc[i][j][q];
                if (d < b1 || (d == b1 && col < i1)) { b2 = b1; b1 = d; i1 = col; }
                else if (d < b2) b2 = d;
            }
#pragma unroll
            for (int off = 1; off < 16; off <<= 1) {
                const float o1 = __shfl_xor(b1, off);
                const int   oi = __shfl_xor(i1, off);
                const float o2 = __shfl_xor(b2, off);
                if (o1 < b1 || (o1 == b1 && oi < i1)) { b2 = fminf(b1, o2); b1 = o1; i1 = oi; }
                else { b2 = fminf(o1, b2); }
            }
            if (cr == 0) { l1v[rl][half] = b1; l2v[rl][half] = b2; liv[rl][half] = i1; }
        }
    }
    __syncthreads();
    if (tid < 128) {
        const float a1 = l1v[tid][0], a2 = l2v[tid][0]; const int ai = liv[tid][0];
        const float c1 = l1v[tid][1], c2 = l2v[tid][1]; const int ci = liv[tid][1];
        float b1, b2; int bi;
        if (c1 < a1 || (c1 == a1 && ci < ai)) { b1 = c1; bi = ci; b2 = fminf(a1, c2); }
        else { b1 = a1; bi = ai; b2 = fminf(c1, a2); }
        const size_t o = (size_t)(m0 + tid) * 4 + blockIdx.x;
        PV[o] = b1; PB[o] = b2; PI[o] = bi;
    }
}

__global__ void argmin_reduce4(const float* __restrict__ PV, const float* __restrict__ PB,
                               const int* __restrict__ PI, int* __restrict__ assign,
                               int* __restrict__ rlist, int* __restrict__ rcount)
{
    const int m = blockIdx.x * 256 + threadIdx.x;
    float b1 = PV[(size_t)m*4], b2 = PB[(size_t)m*4]; int i1 = PI[(size_t)m*4];
#pragma unroll
    for (int s = 1; s < 4; ++s) {
        const float o1 = PV[(size_t)m*4+s], o2 = PB[(size_t)m*4+s];
        const int oi = PI[(size_t)m*4+s];
        if (o1 < b1 || (o1 == b1 && oi < i1)) { b2 = fminf(b1, o2); b1 = o1; i1 = oi; }
        else { b2 = fminf(o1, b2); }
    }
    assign[m] = i1;
    if (b2 - b1 < TAU) { const int p = atomicAdd(rcount, 1); rlist[p] = m; }
}

// -------- exact f32 rescoring of ambiguous rows (bit-identical chain) -------
__global__ __launch_bounds__(256)
void repair_kernel(const float* __restrict__ Z, const float* __restrict__ C,
                   const float* __restrict__ cn2, const float* __restrict__ zn2,
                   const int* __restrict__ rlist, const int* __restrict__ rcount,
                   int* __restrict__ assign)
{
    __shared__ float zrow[256];
    __shared__ float rv[256];
    __shared__ int ri[256];
    const int t = threadIdx.x;
    const int n = rcount[0];
    for (int it = blockIdx.x; it < n; it += gridDim.x) {
        const int m = rlist[it];
        __syncthreads();
        zrow[t] = Z[(size_t)m * D_ + t];
        __syncthreads();
        const float zn = zn2[m];
        float best = 3.4e38f; int bi = 0;
        for (int k = t; k < K_; k += 256) {
            float acc = 0.f;
            for (int d = 0; d < D_; ++d) acc = fmaf(zrow[d], C[(size_t)d * K_ + k], acc);
            const float t1 = zn + cn2[k];
            const float dd = t1 - 2.0f * acc;
            if (dd < best) { best = dd; bi = k; }
        }
        rv[t] = best; ri[t] = bi; __syncthreads();
        for (int s = 128; s > 0; s >>= 1) {
            if (t < s) {
                const float ov = rv[t+s]; const int oi = ri[t+s];
                if (ov < rv[t] || (ov == rv[t] && oi < ri[t])) { rv[t] = ov; ri[t] = oi; }
            }
            __syncthreads();
        }
        if (t == 0) assign[m] = ri[0];
    }
}

// ---------------- fused dense (64x256 tile, full width) + LayerNorm ----------
__global__ __launch_bounds__(256)
void dense_ln_kernel(const float* __restrict__ A, const float* __restrict__ Bw,
                     const float* __restrict__ bias, const float* __restrict__ gamma,
                     const float* __restrict__ beta, float* __restrict__ Z,
                     float* __restrict__ zn2)
{
    __shared__ float As[16][68];
    __shared__ float Bs[16][256];
    __shared__ float rred[64][17];
    __shared__ float rstat[64];
    const int tid = threadIdx.x, tx = tid & 15, ty = tid >> 4;
    const int m0 = blockIdx.x * 64;
    float acc[4][16];
#pragma unroll
    for (int i = 0; i < 4; ++i)
#pragma unroll
        for (int j = 0; j < 16; ++j) acc[i][j] = 0.f;

    const int ar = tid >> 2, ac = (tid & 3) * 4;
    const int br = tid >> 4, bc = (tid & 15) * 16;
    for (int kb = 0; kb < 256; kb += 16) {
        float4 a = *(const float4*)(A + (size_t)(m0 + ar) * 256 + kb + ac);
        As[ac+0][ar] = a.x; As[ac+1][ar] = a.y; As[ac+2][ar] = a.z; As[ac+3][ar] = a.w;
#pragma unroll
        for (int q = 0; q < 4; ++q)
            *(float4*)&Bs[br][bc + q*4] =
                *(const float4*)(Bw + (size_t)(kb + br) * 256 + bc + q*4);
        __syncthreads();
#pragma unroll
        for (int kk = 0; kk < 16; ++kk) {
            float4 a4 = *(const float4*)&As[kk][ty*4];
            float av[4] = {a4.x, a4.y, a4.z, a4.w};
            float bv[16];
#pragma unroll
            for (int q = 0; q < 4; ++q) {
                float4 b4 = *(const float4*)&Bs[kk][q*64 + tx*4];
                bv[q*4+0] = b4.x; bv[q*4+1] = b4.y; bv[q*4+2] = b4.z; bv[q*4+3] = b4.w;
            }
#pragma unroll
            for (int i = 0; i < 4; ++i)
#pragma unroll
                for (int j = 0; j < 16; ++j)
                    acc[i][j] = fmaf(av[i], bv[j], acc[i][j]);
        }
        __syncthreads();
    }

    float bcol[16];
#pragma unroll
    for (int q = 0; q < 4; ++q) {
        float4 b4 = *(const float4*)(bias + q*64 + tx*4);
        bcol[q*4+0] = b4.x; bcol[q*4+1] = b4.y; bcol[q*4+2] = b4.z; bcol[q*4+3] = b4.w;
    }
#pragma unroll
    for (int i = 0; i < 4; ++i)
#pragma unroll
        for (int j = 0; j < 16; ++j) acc[i][j] += bcol[j];

#pragma unroll
    for (int i = 0; i < 4; ++i) {
        float s = 0.f;
#pragma unroll
        for (int j = 0; j < 16; ++j) s += acc[i][j];
        rred[ty*4+i][tx] = s;
    }
    __syncthreads();
    if (tid < 64) {
        float s = 0.f;
#pragma unroll
        for (int t = 0; t < 16; ++t) s += rred[tid][t];
        rstat[tid] = s * (1.f / 256.f);
    }
    __syncthreads();
    float mean_[4];
#pragma unroll
    for (int i = 0; i < 4; ++i) mean_[i] = rstat[ty*4+i];

#pragma unroll
    for (int i = 0; i < 4; ++i) {
        float s = 0.f;
#pragma unroll
        for (int j = 0; j < 16; ++j) { float d = acc[i][j] - mean_[i]; s += d * d; }
        rred[ty*4+i][tx] = s;
    }
    __syncthreads();
    if (tid < 64) {
        float s = 0.f;
#pragma unroll
        for (int t = 0; t < 16; ++t) s += rred[tid][t];
        rstat[tid] = s * (1.f / 256.f);
    }
    __syncthreads();
    float rstd_[4];
#pragma unroll
    for (int i = 0; i < 4; ++i) rstd_[i] = sqrtf(rstat[ty*4+i] + 1e-5f);

    float gam[16], bet[16];
#pragma unroll
    for (int q = 0; q < 4; ++q) {
        float4 g4 = *(const float4*)(gamma + q*64 + tx*4);
        float4 e4 = *(const float4*)(beta  + q*64 + tx*4);
        gam[q*4+0] = g4.x; gam[q*4+1] = g4.y; gam[q*4+2] = g4.z; gam[q*4+3] = g4.w;
        bet[q*4+0] = e4.x; bet[q*4+1] = e4.y; bet[q*4+2] = e4.z; bet[q*4+3] = e4.w;
    }
#pragma unroll
    for (int i = 0; i < 4; ++i)
#pragma unroll
        for (int j = 0; j < 16; ++j) {
            const float d = acc[i][j] - mean_[i];
            acc[i][j] = gam[j] * (d / rstd_[i]) + bet[j];
        }

#pragma unroll
    for (int i = 0; i < 4; ++i) {
        float s = 0.f;
#pragma unroll
        for (int j = 0; j < 16; ++j) s += acc[i][j] * acc[i][j];
        rred[ty*4+i][tx] = s;
    }
    __syncthreads();
    if (tid < 64) {
        float s = 0.f;
#pragma unroll
        for (int t = 0; t < 16; ++t) s += rred[tid][t];
        zn2[m0 + tid] = s;
    }

#pragma unroll
    for (int i = 0; i < 4; ++i) {
        const int row = m0 + ty*4 + i;
#pragma unroll
        for (int q = 0; q < 4; ++q) {
            float4 v;
            v.x = acc[i][q*4+0]; v.y = acc[i][q*4+1];
            v.z = acc[i][q*4+2]; v.w = acc[i][q*4+3];
            *(float4*)(Z + (size_t)row * 256 + q*64 + tx*4) = v;
        }
    }
}

// ---------------- cooperative small-matrix chain -----------------------------
// One 16x16 output tile per (block, job): A (M,Kd) row-major, B (Kd,N) row-major.
__device__ inline float tile16_dot(const float* __restrict__ A, const float* __restrict__ B,
                                   int Kd, int N, int m0, int n0, int tid,
                                   float As[16][68], float Bs[64][20])
{
    const int ty = tid >> 4, tx = tid & 15;
    float acc = 0.f;
    for (int kc = 0; kc < Kd; kc += 64) {
        {
            const int r = tid >> 4, c = (tid & 15) * 4;
            *(float4*)&As[r][c] = *(const float4*)(A + (size_t)(m0 + r) * Kd + kc + c);
            const int r2 = tid >> 2, c2 = (tid & 3) * 4;
            *(float4*)&Bs[r2][c2] = *(const float4*)(B + (size_t)(kc + r2) * N + n0 + c2);
        }
        __syncthreads();
#pragma unroll 16
        for (int kk = 0; kk < 64; ++kk)
            acc = fmaf(As[ty][kk], Bs[kk][tx], acc);
        __syncthreads();
    }
    return acc;
}

__global__ __launch_bounds__(256)
void coop_small(const float* __restrict__ C, float* __restrict__ Ct,
                float* __restrict__ cn2, float* __restrict__ Smat,
                float* __restrict__ Xa, float* __restrict__ Xb,
                float* __restrict__ Tb, float* __restrict__ Ut,
                float* __restrict__ Ainv, float* __restrict__ divPart,
                float* __restrict__ rowAbs)
{
    cg::grid_group gg = cg::this_grid();
    __shared__ float As[16][68];
    __shared__ float Bs[64][20];
    __shared__ float red[256];
    const int b = blockIdx.x, t = threadIdx.x;
    const int gsz = gridDim.x;   // 128

    // P0a: Ct transpose + cn2 (cn2 chain identical to prior rounds)
    for (int idx = b * 256 + t; idx < K_ * D_; idx += gsz * 256) {
        const int k = idx >> 8, d = idx & 255;
        Ct[idx] = C[(size_t)d * K_ + k];
    }
    {
        const int k = b * 256 + t;
        if (k < K_) {
            float s = 0.f;
            for (int d = 0; d < D_; ++d) { float c = C[(size_t)d * K_ + k]; s = fmaf(c, c, s); }
            cn2[k] = s;
        }
    }
    gg.sync();
    // P0b: S = C·C^T + I  (256 tiles)
    for (int tl = b; tl < 256; tl += gsz) {
        const int ti = tl >> 4, tj = tl & 15;
        const float acc = tile16_dot(C, Ct, K_, D_, ti*16, tj*16, t, As, Bs);
        const int row = ti*16 + (t >> 4), col = tj*16 + (t & 15);
        Smat[row * D_ + col] = acc + ((row == col) ? 1.f : 0.f);
    }
    gg.sync();
    // P1: row abs-sums of S
    for (int r = b; r < D_; r += gsz) {
        red[t] = fabsf(Smat[r * D_ + t]); __syncthreads();
        for (int s = 128; s > 0; s >>= 1) { if (t < s) red[t] += red[t+s]; __syncthreads(); }
        if (t == 0) rowAbs[r] = red[0];
        __syncthreads();
    }
    gg.sync();
    // P1b: c0 = 2/(1+max rowAbs); X0 = c0*I
    {
        red[t] = rowAbs[t]; __syncthreads();
        for (int s = 128; s > 0; s >>= 1) { if (t < s) red[t] = fmaxf(red[t], red[t+s]); __syncthreads(); }
        const float c0 = 2.f / (1.f + red[0]);
        __syncthreads();
        for (int idx = b * 256 + t; idx < D_ * D_; idx += gsz * 256) {
            const int i = idx >> 8, j = idx & 255;
            Xa[idx] = (i == j) ? c0 : 0.f;
        }
    }
    gg.sync();
    // NS x6: X <- 2X - X (S X)
    float* Xc = Xa; float* Xn = Xb;
    for (int it = 0; it < 6; ++it) {
        for (int tl = b; tl < 256; tl += gsz) {
            const int ti = tl >> 4, tj = tl & 15;
            const float acc = tile16_dot(Smat, Xc, D_, D_, ti*16, tj*16, t, As, Bs);
            Tb[(ti*16 + (t >> 4)) * D_ + tj*16 + (t & 15)] = acc;
        }
        gg.sync();
        for (int tl = b; tl < 256; tl += gsz) {
            const int ti = tl >> 4, tj = tl & 15;
            const float acc = tile16_dot(Xc, Tb, D_, D_, ti*16, tj*16, t, As, Bs);
            const int row = ti*16 + (t >> 4), col = tj*16 + (t & 15);
            Xn[row * D_ + col] = 2.f * Xc[(size_t)row * D_ + col] - acc;
        }
        gg.sync();
        float* tmp = Xc; Xc = Xn; Xn = tmp;
    }
    // P14: Ut = Ct · Sinv  (512 tiles)
    for (int tl = b; tl < 512; tl += gsz) {
        const int ti = tl >> 4, tj = tl & 15;
        const float acc = tile16_dot(Ct, Xc, D_, D_, ti*16, tj*16, t, As, Bs);
        Ut[(ti*16 + (t >> 4)) * D_ + tj*16 + (t & 15)] = acc;
    }
    gg.sync();
    // P15: Ainv = I - Ut·C  (1024 tiles)
    for (int tl = b; tl < 1024; tl += gsz) {
        const int ti = tl >> 5, tj = tl & 31;
        const float acc = tile16_dot(Ut, C, D_, K_, ti*16, tj*16, t, As, Bs);
        const int row = ti*16 + (t >> 4), col = tj*16 + (t & 15);
        Ainv[(size_t)row * K_ + col] = ((row == col) ? 1.f : 0.f) - acc;
    }
    // P16: diversity partials from G = Ct·C (1024 tiles, no store)
    float dsum = 0.f;
    for (int tl = b; tl < 1024; tl += gsz) {
        const int ti = tl >> 5, tj = tl & 31;
        const float acc = tile16_dot(Ct, C, D_, K_, ti*16, tj*16, t, As, Bs);
        const int row = ti*16 + (t >> 4), col = tj*16 + (t & 15);
        if (row != col) {
            const float ri = 1.f / sqrtf(fmaxf(cn2[row], 1e-12f));
            const float rj = 1.f / sqrtf(fmaxf(cn2[col], 1e-12f));
            dsum += fmaxf(acc * ri * rj, 0.f);
        }
    }
    red[t] = dsum; __syncthreads();
    for (int s = 128; s > 0; s >>= 1) { if (t < s) red[t] += red[t+s]; __syncthreads(); }
    if (t == 0) divPart[b] = red[0];
}

// ---------------- simplex projection, Michelot, one wave per row -------------
__global__ __launch_bounds__(256)
void project_kernel(float* P)
{
    const int wave = threadIdx.x >> 6;
    const int lane = threadIdx.x & 63;
    const int row = blockIdx.x * 4 + wave;
    const size_t base = (size_t)row * K_ + lane;
    float v[8];
#pragma unroll
    for (int j = 0; j < 8; ++j) v[j] = P[base + j * 64];

    float s = 0.f;
#pragma unroll
    for (int j = 0; j < 8; ++j) s += v[j];
    for (int off = 32; off > 0; off >>= 1) s += __shfl_xor(s, off);

    float theta = (s - 1.f) * (1.f / 512.f);
    int cnt = K_;
    for (int it = 0; it < K_; ++it) {
        float ls = 0.f; int lc = 0;
#pragma unroll
        for (int j = 0; j < 8; ++j)
            if (v[j] > theta) { ls += v[j]; ++lc; }
        for (int off = 32; off > 0; off >>= 1) {
            ls += __shfl_xor(ls, off);
            lc += __shfl_xor(lc, off);
        }
        if (lc == cnt) break;
        theta = (ls - 1.f) / (float)lc;
        cnt = lc;
    }
#pragma unroll
    for (int j = 0; j < 8; ++j) P[base + j * 64] = fmaxf(v[j] - theta, 0.f);
}

// ---------------- column partial sums of P (for p_j) -------------------------
__global__ __launch_bounds__(512)
void colsum_kernel(const float* __restrict__ P, float* __restrict__ part)
{
    const int k = threadIdx.x;
    const int b = blockIdx.x;
    float s = 0.f;
    const size_t base = (size_t)b * 128 * K_ + k;
    for (int r = 0; r < 128; ++r) s += P[base + (size_t)r * K_];
    part[(size_t)b * K_ + k] = s;
}

// ---------------- finalize (slim): scalars only ------------------------------
#define BLOCK_REDUCE_512(val, result) \
    red[t] = (val); __syncthreads(); \
    for (int s_ = 256; s_ > 0; s_ >>= 1) { if (t < s_) red[t] += red[t + s_]; __syncthreads(); } \
    result = red[0]; __syncthreads();

__global__ __launch_bounds__(512)
void finalize_kernel(const float* __restrict__ part, const float* __restrict__ divPart,
                     const float* __restrict__ lossPart, float* __restrict__ out_scal)
{
    __shared__ float red[512];
    const int t = threadIdx.x;

    float praw = 0.f;
    for (int b = 0; b < 256; ++b) praw += part[b * K_ + t];
    const float pm = praw * (1.f / 32768.f);

    const float pj = fminf(fmaxf(pm, 1e-10f), 1.0f);
    float sp; BLOCK_REDUCE_512(pj, sp);
    const float pjn = pj / sp;
    float Hbits; BLOCK_REDUCE_512(-pjn * logf(pjn) / 0.69314718056f, Hbits);

    float spm; BLOCK_REDUCE_512(pm, spm);
    const float s2 = spm + 1e-5f;
    const float pmn = pm / s2;
    float ereg; BLOCK_REDUCE_512(-pmn * logf(pmn + 1e-5f), ereg);

    float dv = (t < 128) ? divPart[t] : 0.f;
    float divs; BLOCK_REDUCE_512(dv, divs);
    const float divloss = divs * (1.f / 262144.f);

    float lp = lossPart[t];
    float prim; BLOCK_REDUCE_512(lp, prim);
    prim *= 1.f / 8388608.f;

    if (t == 0) {
        out_scal[0] = prim + 0.5f * ereg + 0.5f * divloss;
        out_scal[1] = exp2f(Hbits);
    }
}

// ---------------- launch -----------------------------------------------------
extern "C" void kernel_launch(void* const* d_in, const int* in_sizes, int n_in,
                              void* d_out, int out_size, void* d_ws, size_t ws_size,
                              hipStream_t stream)
{
    const float* inputs = (const float*)d_in[0];
    const float* gamma  = (const float*)d_in[1];
    const float* beta   = (const float*)d_in[2];
    const float* C      = (const float*)d_in[3];   // (D,K)
    const float* d_w    = (const float*)d_in[4];   // (D,D)
    const float* d_b    = (const float*)d_in[5];   // (D,)

    float* out = (float*)d_out;
    float* Z = out;                                 // M*D slot (Z, later Zq)
    float* P = out + (size_t)M_ * D_;               // M*K slot (P_sol -> P_proj)
    float* out_scal = P + (size_t)M_ * K_;          // loss, perplexity

    float* w = (float*)d_ws;
    float* Smat = w;     w += D_ * D_;
    float* Xa   = w;     w += D_ * D_;
    float* Xb   = w;     w += D_ * D_;
    float* Tb   = w;     w += D_ * D_;
    float* Ut   = w;     w += K_ * D_;              // C^T Sinv  (512x256)
    float* Ainv = w;     w += K_ * K_;
    float* Ct   = w;     w += K_ * D_;
    float* cn2  = w;     w += K_;
    float* zn2  = w;     w += M_;
    float* part = w;     w += 256 * K_;
    float* lossPart = w; w += 512;
    float* divPart  = w; w += 128;
    float* rowAbs   = w; w += 256;
    float* PV   = w;     w += M_ * 4;
    float* PB   = w;     w += M_ * 4;
    int* PI     = (int*)w; w += M_ * 4;
    int* rlist  = (int*)w; w += M_;
    int* rcount = (int*)w; w += 16;
    int* assign = (int*)w;

    hipMemsetAsync(rcount, 0, sizeof(int), stream);

    // 1. Z = LN(inputs @ d_w + d_b), zn2    (f32, argmin-critical)
    dense_ln_kernel<<<M_/64, 256, 0, stream>>>(inputs, d_w, d_b, gamma, beta, Z, zn2);

    // 2. cooperative small-matrix chain
    {
        void* args[] = {(void*)&C, (void*)&Ct, (void*)&cn2, (void*)&Smat,
                        (void*)&Xa, (void*)&Xb, (void*)&Tb, (void*)&Ut,
                        (void*)&Ainv, (void*)&divPart, (void*)&rowAbs};
        hipLaunchCooperativeKernel((void*)coop_small, dim3(128), dim3(256),
                                   args, 0, stream);
    }

    // 3. approx dists (split-bf16 MFMA) + top-2 -> provisional assign + repair set
    score_mfma_argmin<<<dim3(K_/128, M_/128), 256, 0, stream>>>(Z, Ct, cn2, zn2, PV, PB, PI);
    argmin_reduce4<<<M_/256, 256, 0, stream>>>(PV, PB, PI, assign, rlist, rcount);
    repair_kernel<<<256, 256, 0, stream>>>(Z, C, cn2, zn2, rlist, rcount, assign);

    // 4. P_sol^T = Z @ Ut^T + Ainv[assign,:]   (split-bf16 MFMA)
    mfma_gemm<2><<<dim3(K_/128, M_/128), 256, 0, stream>>>(
        Z, Ut, P, D_, K_, Ainv, assign, nullptr, nullptr);
    // 5. simplex projection in place
    project_kernel<<<M_/4, 256, 0, stream>>>(P);
    // 6. column partial sums
    colsum_kernel<<<256, 512, 0, stream>>>(P, part);
    // 7. Zq = P @ C^T (split-bf16 MFMA; B^T = C), loss partials
    mfma_gemm<3><<<dim3(D_/128, M_/128), 256, 0, stream>>>(
        P, C, Z, K_, D_, nullptr, nullptr, Z, lossPart);
    // 8. scalars
    finalize_kernel<<<1, 512, 0, stream>>>(part, divPart, lossPart, out_scal);

    (void)in_sizes; (void)n_in; (void)out_size; (void)ws_size;
}

// Round 5
// 696.620 us; speedup vs baseline: 1.2016x; 1.2016x over previous
//
#include <hip/hip_runtime.h>
#include <math.h>

// SCQ layer forward.
//   dense+LN f32 (argmin-critical Z bits).
//   small-matrix chain: separate small_gemm launches (round-3 structure;
//   cooperative single-kernel version was 4.7x slower - latency-bound).
//   score: split-bf16 MFMA approx dists + per-row top-2; rows with gap < TAU
//   repaired by bit-exact f32 rescoring (same fmaf order as the f32 path).
//   post-argmin GEMMs (P_sol, Zq) split-bf16 x3 MFMA.

#define M_ 32768
#define D_ 256
#define K_ 512
#define TAU 0.02f

typedef short bf16x8 __attribute__((ext_vector_type(8)));
typedef unsigned short u16x8 __attribute__((ext_vector_type(8)));
typedef float f32x4 __attribute__((ext_vector_type(4)));

#define LSTR 56   // LDS row stride (ushorts)

// split 16 consecutive f32 into bf16 hi/lo planes (truncation split)
__device__ inline void stage16(const float* __restrict__ g,
                               unsigned short* __restrict__ lh,
                               unsigned short* __restrict__ ll)
{
    unsigned short hi[16], lo[16];
#pragma unroll
    for (int q = 0; q < 4; ++q) {
        float4 v = ((const float4*)g)[q];
        float f[4] = {v.x, v.y, v.z, v.w};
#pragma unroll
        for (int e = 0; e < 4; ++e) {
            unsigned int u = __float_as_uint(f[e]);
            unsigned short h = (unsigned short)(u >> 16);
            float fh = __uint_as_float(((unsigned int)h) << 16);
            float r = f[e] - fh;
            unsigned short l = (unsigned short)(__float_as_uint(r) >> 16);
            hi[q*4+e] = h; lo[q*4+e] = l;
        }
    }
    *(u16x8*)lh       = *(u16x8*)hi;
    *(u16x8*)(lh + 8) = *(u16x8*)(hi + 8);
    *(u16x8*)ll       = *(u16x8*)lo;
    *(u16x8*)(ll + 8) = *(u16x8*)(lo + 8);
}

// ---- MFMA GEMM: Out(MxN) = A(MxKd) @ Bt^T, Bt is (N x Kd) row-major --------
// EPI: 2 = +Ainv[assign[row],col] (psol, N=512); 3 = Zq + loss partials (N=256)
template<int EPI>
__global__ __launch_bounds__(256)
void mfma_gemm(const float* __restrict__ A, const float* __restrict__ Bt,
               float* __restrict__ Out, int Kd, int N,
               const float* __restrict__ AinvM, const int* __restrict__ assign,
               const float* Zref, float* __restrict__ lossPart)
{
    __shared__ unsigned short sAh[128*LSTR], sAl[128*LSTR];
    __shared__ unsigned short sBh[128*LSTR], sBl[128*LSTR];
    __shared__ float red[256];
    const int tid = threadIdx.x;
    const int m0 = blockIdx.y * 128, n0 = blockIdx.x * 128;
    const int w = tid >> 6, lane = tid & 63;
    const int wr = (w & 1) * 64, wc = (w >> 1) * 64;
    const int cg = lane >> 4, cr = lane & 15;

    f32x4 acc[4][4];
    const f32x4 z4 = {0.f, 0.f, 0.f, 0.f};
#pragma unroll
    for (int i = 0; i < 4; ++i)
#pragma unroll
        for (int j = 0; j < 4; ++j) acc[i][j] = z4;

    const int sr = tid >> 1;
    const int sk = (tid & 1) * 16;
    const float* Ag = A  + (size_t)(m0 + sr) * Kd + sk;
    const float* Bg = Bt + (size_t)(n0 + sr) * Kd + sk;
    const int soff = sr * LSTR + sk;

    for (int kb = 0; kb < Kd; kb += 32) {
        stage16(Ag + kb, sAh + soff, sAl + soff);
        stage16(Bg + kb, sBh + soff, sBl + soff);
        __syncthreads();
        bf16x8 ah[4], al[4], bh[4], bl[4];
#pragma unroll
        for (int f = 0; f < 4; ++f) {
            const int ao = (wr + f*16 + cr) * LSTR + cg*8;
            ah[f] = *(const bf16x8*)&sAh[ao];
            al[f] = *(const bf16x8*)&sAl[ao];
            const int bo = (wc + f*16 + cr) * LSTR + cg*8;
            bh[f] = *(const bf16x8*)&sBh[bo];
            bl[f] = *(const bf16x8*)&sBl[bo];
        }
#pragma unroll
        for (int i = 0; i < 4; ++i)
#pragma unroll
            for (int j = 0; j < 4; ++j) {
                acc[i][j] = __builtin_amdgcn_mfma_f32_16x16x32_bf16(ah[i], bh[j], acc[i][j], 0, 0, 0);
                acc[i][j] = __builtin_amdgcn_mfma_f32_16x16x32_bf16(al[i], bh[j], acc[i][j], 0, 0, 0);
                acc[i][j] = __builtin_amdgcn_mfma_f32_16x16x32_bf16(ah[i], bl[j], acc[i][j], 0, 0, 0);
            }
        __syncthreads();
    }

    if (EPI == 2) {
#pragma unroll
        for (int i = 0; i < 4; ++i) {
#pragma unroll
            for (int q = 0; q < 4; ++q) {
                const int row = m0 + wr + i*16 + cg*4 + q;
                const int am = assign[row];
                const float* Arow = AinvM + (size_t)am * K_ + n0 + wc;
#pragma unroll
                for (int j = 0; j < 4; ++j)
                    Out[(size_t)row * N + n0 + wc + j*16 + cr] =
                        acc[i][j][q] + Arow[j*16 + cr];
            }
        }
    } else {
        float lsum = 0.f;
#pragma unroll
        for (int i = 0; i < 4; ++i) {
#pragma unroll
            for (int q = 0; q < 4; ++q) {
                const int row = m0 + wr + i*16 + cg*4 + q;
#pragma unroll
                for (int j = 0; j < 4; ++j) {
                    const int col = n0 + wc + j*16 + cr;
                    const float v = acc[i][j][q];
                    const float zv = Zref[(size_t)row * N + col];
                    const float d = v - zv;
                    lsum += d * d;
                    Out[(size_t)row * N + col] = v;
                }
            }
        }
        red[tid] = lsum;
        __syncthreads();
        for (int s = 128; s > 0; s >>= 1) {
            if (tid < s) red[tid] += red[tid + s];
            __syncthreads();
        }
        if (tid == 0) lossPart[blockIdx.y * gridDim.x + blockIdx.x] = red[0];
    }
}

// -------- score: split-bf16 MFMA dists + per-row per-stripe top-2 -----------
__global__ __launch_bounds__(256)
void score_mfma_argmin(const float* __restrict__ A, const float* __restrict__ Bt,
                       const float* __restrict__ cn2, const float* __restrict__ zn2,
                       float* __restrict__ PV, float* __restrict__ PB,
                       int* __restrict__ PI)
{
    __shared__ unsigned short sAh[128*LSTR], sAl[128*LSTR];
    __shared__ unsigned short sBh[128*LSTR], sBl[128*LSTR];
    __shared__ float l1v[128][2], l2v[128][2];
    __shared__ int   liv[128][2];
    const int tid = threadIdx.x;
    const int m0 = blockIdx.y * 128, n0 = blockIdx.x * 128;
    const int w = tid >> 6, lane = tid & 63;
    const int wr = (w & 1) * 64, wc = (w >> 1) * 64;
    const int cg = lane >> 4, cr = lane & 15;

    f32x4 acc[4][4];
    const f32x4 z4 = {0.f, 0.f, 0.f, 0.f};
#pragma unroll
    for (int i = 0; i < 4; ++i)
#pragma unroll
        for (int j = 0; j < 4; ++j) acc[i][j] = z4;

    const int sr = tid >> 1;
    const int sk = (tid & 1) * 16;
    const float* Ag = A  + (size_t)(m0 + sr) * D_ + sk;
    const float* Bg = Bt + (size_t)(n0 + sr) * D_ + sk;
    const int soff = sr * LSTR + sk;

    for (int kb = 0; kb < D_; kb += 32) {
        stage16(Ag + kb, sAh + soff, sAl + soff);
        stage16(Bg + kb, sBh + soff, sBl + soff);
        __syncthreads();
        bf16x8 ah[4], al[4], bh[4], bl[4];
#pragma unroll
        for (int f = 0; f < 4; ++f) {
            const int ao = (wr + f*16 + cr) * LSTR + cg*8;
            ah[f] = *(const bf16x8*)&sAh[ao];
            al[f] = *(const bf16x8*)&sAl[ao];
            const int bo = (wc + f*16 + cr) * LSTR + cg*8;
            bh[f] = *(const bf16x8*)&sBh[bo];
            bl[f] = *(const bf16x8*)&sBl[bo];
        }
#pragma unroll
        for (int i = 0; i < 4; ++i)
#pragma unroll
            for (int j = 0; j < 4; ++j) {
                acc[i][j] = __builtin_amdgcn_mfma_f32_16x16x32_bf16(ah[i], bh[j], acc[i][j], 0, 0, 0);
                acc[i][j] = __builtin_amdgcn_mfma_f32_16x16x32_bf16(al[i], bh[j], acc[i][j], 0, 0, 0);
                acc[i][j] = __builtin_amdgcn_mfma_f32_16x16x32_bf16(ah[i], bl[j], acc[i][j], 0, 0, 0);
            }
        __syncthreads();
    }

    const int half = wc >> 6;
#pragma unroll
    for (int i = 0; i < 4; ++i) {
#pragma unroll
        for (int q = 0; q < 4; ++q) {
            const int rl = wr + i*16 + cg*4 + q;
            const float zr = zn2[m0 + rl];
            float b1 = 3.4e38f, b2 = 3.4e38f; int i1 = 0x7fffffff;
#pragma unroll
            for (int j = 0; j < 4; ++j) {
                const int col = n0 + wc + j*16 + cr;
                const float d = (zr + cn2[col]) - 2.0f * acc[i][j][q];
                if (d < b1 || (d == b1 && col < i1)) { b2 = b1; b1 = d; i1 = col; }
                else if (d < b2) b2 = d;
            }
#pragma unroll
            for (int off = 1; off < 16; off <<= 1) {
                const float o1 = __shfl_xor(b1, off);
                const int   oi = __shfl_xor(i1, off);
                const float o2 = __shfl_xor(b2, off);
                if (o1 < b1 || (o1 == b1 && oi < i1)) { b2 = fminf(b1, o2); b1 = o1; i1 = oi; }
                else { b2 = fminf(o1, b2); }
            }
            if (cr == 0) { l1v[rl][half] = b1; l2v[rl][half] = b2; liv[rl][half] = i1; }
        }
    }
    __syncthreads();
    if (tid < 128) {
        const float a1 = l1v[tid][0], a2 = l2v[tid][0]; const int ai = liv[tid][0];
        const float c1 = l1v[tid][1], c2 = l2v[tid][1]; const int ci = liv[tid][1];
        float b1, b2; int bi;
        if (c1 < a1 || (c1 == a1 && ci < ai)) { b1 = c1; bi = ci; b2 = fminf(a1, c2); }
        else { b1 = a1; bi = ai; b2 = fminf(c1, a2); }
        const size_t o = (size_t)(m0 + tid) * 4 + blockIdx.x;
        PV[o] = b1; PB[o] = b2; PI[o] = bi;
    }
}

__global__ void argmin_reduce4(const float* __restrict__ PV, const float* __restrict__ PB,
                               const int* __restrict__ PI, int* __restrict__ assign,
                               int* __restrict__ rlist, int* __restrict__ rcount)
{
    const int m = blockIdx.x * 256 + threadIdx.x;
    float b1 = PV[(size_t)m*4], b2 = PB[(size_t)m*4]; int i1 = PI[(size_t)m*4];
#pragma unroll
    for (int s = 1; s < 4; ++s) {
        const float o1 = PV[(size_t)m*4+s], o2 = PB[(size_t)m*4+s];
        const int oi = PI[(size_t)m*4+s];
        if (o1 < b1 || (o1 == b1 && oi < i1)) { b2 = fminf(b1, o2); b1 = o1; i1 = oi; }
        else { b2 = fminf(o1, b2); }
    }
    assign[m] = i1;
    if (b2 - b1 < TAU) { const int p = atomicAdd(rcount, 1); rlist[p] = m; }
}

// -------- exact f32 rescoring of ambiguous rows (bit-identical chain) -------
// Uses Ct (K x D row-major): same product values, same fmaf order as the f32
// reference chain C[d*K+k] -> bit-identical dists.
__global__ __launch_bounds__(256)
void repair_kernel(const float* __restrict__ Z, const float* __restrict__ Ct,
                   const float* __restrict__ cn2, const float* __restrict__ zn2,
                   const int* __restrict__ rlist, const int* __restrict__ rcount,
                   int* __restrict__ assign)
{
    __shared__ float zrow[256];
    __shared__ float rv[256];
    __shared__ int ri[256];
    const int t = threadIdx.x;
    const int n = rcount[0];
    for (int it = blockIdx.x; it < n; it += gridDim.x) {
        const int m = rlist[it];
        __syncthreads();
        zrow[t] = Z[(size_t)m * D_ + t];
        __syncthreads();
        const float zn = zn2[m];
        float best = 3.4e38f; int bi = 0;
        for (int k = t; k < K_; k += 256) {
            const float* crow = Ct + (size_t)k * D_;
            float acc = 0.f;
            for (int d = 0; d < D_; ++d) acc = fmaf(zrow[d], crow[d], acc);
            const float t1 = zn + cn2[k];
            const float dd = t1 - 2.0f * acc;
            if (dd < best) { best = dd; bi = k; }
        }
        rv[t] = best; ri[t] = bi; __syncthreads();
        for (int s = 128; s > 0; s >>= 1) {
            if (t < s) {
                const float ov = rv[t+s]; const int oi = ri[t+s];
                if (ov < rv[t] || (ov == rv[t] && oi < ri[t])) { rv[t] = ov; ri[t] = oi; }
            }
            __syncthreads();
        }
        if (t == 0) assign[m] = ri[0];
    }
}

// ---------------- fused dense (64x256 tile, full width) + LayerNorm ----------
__global__ __launch_bounds__(256)
void dense_ln_kernel(const float* __restrict__ A, const float* __restrict__ Bw,
                     const float* __restrict__ bias, const float* __restrict__ gamma,
                     const float* __restrict__ beta, float* __restrict__ Z,
                     float* __restrict__ zn2)
{
    __shared__ float As[16][68];
    __shared__ float Bs[16][256];
    __shared__ float rred[64][17];
    __shared__ float rstat[64];
    const int tid = threadIdx.x, tx = tid & 15, ty = tid >> 4;
    const int m0 = blockIdx.x * 64;
    float acc[4][16];
#pragma unroll
    for (int i = 0; i < 4; ++i)
#pragma unroll
        for (int j = 0; j < 16; ++j) acc[i][j] = 0.f;

    const int ar = tid >> 2, ac = (tid & 3) * 4;
    const int br = tid >> 4, bc = (tid & 15) * 16;
    for (int kb = 0; kb < 256; kb += 16) {
        float4 a = *(const float4*)(A + (size_t)(m0 + ar) * 256 + kb + ac);
        As[ac+0][ar] = a.x; As[ac+1][ar] = a.y; As[ac+2][ar] = a.z; As[ac+3][ar] = a.w;
#pragma unroll
        for (int q = 0; q < 4; ++q)
            *(float4*)&Bs[br][bc + q*4] =
                *(const float4*)(Bw + (size_t)(kb + br) * 256 + bc + q*4);
        __syncthreads();
#pragma unroll
        for (int kk = 0; kk < 16; ++kk) {
            float4 a4 = *(const float4*)&As[kk][ty*4];
            float av[4] = {a4.x, a4.y, a4.z, a4.w};
            float bv[16];
#pragma unroll
            for (int q = 0; q < 4; ++q) {
                float4 b4 = *(const float4*)&Bs[kk][q*64 + tx*4];
                bv[q*4+0] = b4.x; bv[q*4+1] = b4.y; bv[q*4+2] = b4.z; bv[q*4+3] = b4.w;
            }
#pragma unroll
            for (int i = 0; i < 4; ++i)
#pragma unroll
                for (int j = 0; j < 16; ++j)
                    acc[i][j] = fmaf(av[i], bv[j], acc[i][j]);
        }
        __syncthreads();
    }

    float bcol[16];
#pragma unroll
    for (int q = 0; q < 4; ++q) {
        float4 b4 = *(const float4*)(bias + q*64 + tx*4);
        bcol[q*4+0] = b4.x; bcol[q*4+1] = b4.y; bcol[q*4+2] = b4.z; bcol[q*4+3] = b4.w;
    }
#pragma unroll
    for (int i = 0; i < 4; ++i)
#pragma unroll
        for (int j = 0; j < 16; ++j) acc[i][j] += bcol[j];

#pragma unroll
    for (int i = 0; i < 4; ++i) {
        float s = 0.f;
#pragma unroll
        for (int j = 0; j < 16; ++j) s += acc[i][j];
        rred[ty*4+i][tx] = s;
    }
    __syncthreads();
    if (tid < 64) {
        float s = 0.f;
#pragma unroll
        for (int t = 0; t < 16; ++t) s += rred[tid][t];
        rstat[tid] = s * (1.f / 256.f);
    }
    __syncthreads();
    float mean_[4];
#pragma unroll
    for (int i = 0; i < 4; ++i) mean_[i] = rstat[ty*4+i];

#pragma unroll
    for (int i = 0; i < 4; ++i) {
        float s = 0.f;
#pragma unroll
        for (int j = 0; j < 16; ++j) { float d = acc[i][j] - mean_[i]; s += d * d; }
        rred[ty*4+i][tx] = s;
    }
    __syncthreads();
    if (tid < 64) {
        float s = 0.f;
#pragma unroll
        for (int t = 0; t < 16; ++t) s += rred[tid][t];
        rstat[tid] = s * (1.f / 256.f);
    }
    __syncthreads();
    float rstd_[4];
#pragma unroll
    for (int i = 0; i < 4; ++i) rstd_[i] = sqrtf(rstat[ty*4+i] + 1e-5f);

    float gam[16], bet[16];
#pragma unroll
    for (int q = 0; q < 4; ++q) {
        float4 g4 = *(const float4*)(gamma + q*64 + tx*4);
        float4 e4 = *(const float4*)(beta  + q*64 + tx*4);
        gam[q*4+0] = g4.x; gam[q*4+1] = g4.y; gam[q*4+2] = g4.z; gam[q*4+3] = g4.w;
        bet[q*4+0] = e4.x; bet[q*4+1] = e4.y; bet[q*4+2] = e4.z; bet[q*4+3] = e4.w;
    }
#pragma unroll
    for (int i = 0; i < 4; ++i)
#pragma unroll
        for (int j = 0; j < 16; ++j) {
            const float d = acc[i][j] - mean_[i];
            acc[i][j] = gam[j] * (d / rstd_[i]) + bet[j];
        }

#pragma unroll
    for (int i = 0; i < 4; ++i) {
        float s = 0.f;
#pragma unroll
        for (int j = 0; j < 16; ++j) s += acc[i][j] * acc[i][j];
        rred[ty*4+i][tx] = s;
    }
    __syncthreads();
    if (tid < 64) {
        float s = 0.f;
#pragma unroll
        for (int t = 0; t < 16; ++t) s += rred[tid][t];
        zn2[m0 + tid] = s;
    }

#pragma unroll
    for (int i = 0; i < 4; ++i) {
        const int row = m0 + ty*4 + i;
#pragma unroll
        for (int q = 0; q < 4; ++q) {
            float4 v;
            v.x = acc[i][q*4+0]; v.y = acc[i][q*4+1];
            v.z = acc[i][q*4+2]; v.w = acc[i][q*4+3];
            *(float4*)(Z + (size_t)row * 256 + q*64 + tx*4) = v;
        }
    }
}

// ---------------- small GEMM: 64x64 tiles -----------------------------------
// TRA=0: A is (M,Kd).  TRA=1: A is (Kd,M) (Out = A^T B).  B is (Kd,N).
// EPI: 0 none; 1: 2*E - acc; 2: I - acc; 3: acc + I; 4: diversity partials
template<int TRA, int EPI>
__global__ __launch_bounds__(256)
void small_gemm(const float* __restrict__ A, const float* __restrict__ B,
                const float* __restrict__ E, float* __restrict__ Out,
                int M, int N, int Kd,
                const float* __restrict__ cn2, float* __restrict__ divPart)
{
    __shared__ float As[16][68];
    __shared__ float Bs[16][68];
    __shared__ float red2[256];
    const int tid = threadIdx.x;
    const int tx = tid & 15, ty = tid >> 4;
    const int n0 = blockIdx.x * 64, m0 = blockIdx.y * 64;
    float acc[4][4];
#pragma unroll
    for (int i = 0; i < 4; ++i)
#pragma unroll
        for (int j = 0; j < 4; ++j) acc[i][j] = 0.f;

    for (int kb = 0; kb < Kd; kb += 16) {
        if (TRA == 0) {
            const int ar2 = tid >> 2, ac2 = (tid & 3) * 4;
            float4 a = *(const float4*)(A + (size_t)(m0 + ar2) * Kd + kb + ac2);
            As[ac2+0][ar2] = a.x; As[ac2+1][ar2] = a.y;
            As[ac2+2][ar2] = a.z; As[ac2+3][ar2] = a.w;
        } else {
            const int ar2 = tid >> 4, ac2 = (tid & 15) * 4;
            float4 a = *(const float4*)(A + (size_t)(kb + ar2) * M + m0 + ac2);
            *(float4*)&As[ar2][ac2] = a;
        }
        {
            const int br2 = tid >> 4, bc2 = (tid & 15) * 4;
            float4 b = *(const float4*)(B + (size_t)(kb + br2) * N + n0 + bc2);
            *(float4*)&Bs[br2][bc2] = b;
        }
        __syncthreads();
#pragma unroll
        for (int kk = 0; kk < 16; ++kk) {
            float4 a4 = *(const float4*)&As[kk][ty*4];
            float4 b4 = *(const float4*)&Bs[kk][tx*4];
            float a_[4] = {a4.x, a4.y, a4.z, a4.w};
            float b_[4] = {b4.x, b4.y, b4.z, b4.w};
#pragma unroll
            for (int i = 0; i < 4; ++i)
#pragma unroll
                for (int j = 0; j < 4; ++j)
                    acc[i][j] = fmaf(a_[i], b_[j], acc[i][j]);
        }
        __syncthreads();
    }
    if (EPI == 4) {
        float dsum = 0.f;
#pragma unroll
        for (int i = 0; i < 4; ++i) {
            const int row = m0 + ty*4 + i;
            const float ri = 1.f / sqrtf(fmaxf(cn2[row], 1e-12f));
#pragma unroll
            for (int j = 0; j < 4; ++j) {
                const int col = n0 + tx*4 + j;
                if (row != col) {
                    const float rj = 1.f / sqrtf(fmaxf(cn2[col], 1e-12f));
                    dsum += fmaxf(acc[i][j] * ri * rj, 0.f);
                }
            }
        }
        red2[tid] = dsum;
        __syncthreads();
        for (int s = 128; s > 0; s >>= 1) {
            if (tid < s) red2[tid] += red2[tid + s];
            __syncthreads();
        }
        if (tid == 0) divPart[blockIdx.y * gridDim.x + blockIdx.x] = red2[0];
        return;
    }
#pragma unroll
    for (int i = 0; i < 4; ++i) {
        const int row = m0 + ty*4 + i;
#pragma unroll
        for (int j = 0; j < 4; ++j) {
            const int col = n0 + tx*4 + j;
            float v = acc[i][j];
            if (EPI == 1) v = 2.f * E[(size_t)row * N + col] - v;
            else if (EPI == 2) v = ((row == col) ? 1.f : 0.f) - v;
            else if (EPI == 3) v = v + ((row == col) ? 1.f : 0.f);
            Out[(size_t)row * N + col] = v;
        }
    }
}

// ---------------- Ct = C^T ; column norms of C -------------------------------
__global__ void transpose_ct(const float* __restrict__ C, float* __restrict__ Ct)
{
    const int idx = blockIdx.x * 256 + threadIdx.x;
    const int k = idx >> 8, d = idx & 255;
    Ct[idx] = C[(size_t)d * K_ + k];
}

__global__ void cn2_kernel(const float* __restrict__ C, float* __restrict__ cn2)
{
    const int k = blockIdx.x * 256 + threadIdx.x;
    float s = 0.f;
    for (int d = 0; d < D_; ++d) { float c = C[(size_t)d * K_ + k]; s = fmaf(c, c, s); }
    cn2[k] = s;
}

// ------------- ||S||_inf (via symmetry: column sums) -> X0 = c*I -------------
__global__ void scal_init_kernel(const float* __restrict__ S, float* __restrict__ X)
{
    __shared__ float red[256];
    const int t = threadIdx.x;
    float s = 0.f;
    for (int q = 0; q < D_; ++q) s += fabsf(S[(size_t)q * D_ + t]);
    red[t] = s; __syncthreads();
    for (int sh = 128; sh > 0; sh >>= 1) {
        if (t < sh) red[t] = fmaxf(red[t], red[t + sh]);
        __syncthreads();
    }
    const float c = 2.f / (1.f + red[0]);
    for (int idx = t; idx < D_ * D_; idx += 256) {
        const int i = idx >> 8, j = idx & 255;
        X[idx] = (i == j) ? c : 0.f;
    }
}

// ---------------- simplex projection, Michelot, one wave per row -------------
__global__ __launch_bounds__(256)
void project_kernel(float* P)
{
    const int wave = threadIdx.x >> 6;
    const int lane = threadIdx.x & 63;
    const int row = blockIdx.x * 4 + wave;
    const size_t base = (size_t)row * K_ + lane;
    float v[8];
#pragma unroll
    for (int j = 0; j < 8; ++j) v[j] = P[base + j * 64];

    float s = 0.f;
#pragma unroll
    for (int j = 0; j < 8; ++j) s += v[j];
    for (int off = 32; off > 0; off >>= 1) s += __shfl_xor(s, off);

    float theta = (s - 1.f) * (1.f / 512.f);
    int cnt = K_;
    for (int it = 0; it < K_; ++it) {
        float ls = 0.f; int lc = 0;
#pragma unroll
        for (int j = 0; j < 8; ++j)
            if (v[j] > theta) { ls += v[j]; ++lc; }
        for (int off = 32; off > 0; off >>= 1) {
            ls += __shfl_xor(ls, off);
            lc += __shfl_xor(lc, off);
        }
        if (lc == cnt) break;
        theta = (ls - 1.f) / (float)lc;
        cnt = lc;
    }
#pragma unroll
    for (int j = 0; j < 8; ++j) P[base + j * 64] = fmaxf(v[j] - theta, 0.f);
}

// ---------------- column partial sums of P (for p_j) -------------------------
__global__ __launch_bounds__(512)
void colsum_kernel(const float* __restrict__ P, float* __restrict__ part)
{
    const int k = threadIdx.x;
    const int b = blockIdx.x;
    float s = 0.f;
    const size_t base = (size_t)b * 128 * K_ + k;
    for (int r = 0; r < 128; ++r) s += P[base + (size_t)r * K_];
    part[(size_t)b * K_ + k] = s;
}

// ---------------- finalize (slim): scalars only ------------------------------
#define BLOCK_REDUCE_512(val, result) \
    red[t] = (val); __syncthreads(); \
    for (int s_ = 256; s_ > 0; s_ >>= 1) { if (t < s_) red[t] += red[t + s_]; __syncthreads(); } \
    result = red[0]; __syncthreads();

__global__ __launch_bounds__(512)
void finalize_kernel(const float* __restrict__ part, const float* __restrict__ divPart,
                     const float* __restrict__ lossPart, float* __restrict__ out_scal)
{
    __shared__ float red[512];
    const int t = threadIdx.x;

    float praw = 0.f;
    for (int b = 0; b < 256; ++b) praw += part[b * K_ + t];
    const float pm = praw * (1.f / 32768.f);

    const float pj = fminf(fmaxf(pm, 1e-10f), 1.0f);
    float sp; BLOCK_REDUCE_512(pj, sp);
    const float pjn = pj / sp;
    float Hbits; BLOCK_REDUCE_512(-pjn * logf(pjn) / 0.69314718056f, Hbits);

    float spm; BLOCK_REDUCE_512(pm, spm);
    const float s2 = spm + 1e-5f;
    const float pmn = pm / s2;
    float ereg; BLOCK_REDUCE_512(-pmn * logf(pmn + 1e-5f), ereg);

    float dv = (t < 64) ? divPart[t] : 0.f;
    float divs; BLOCK_REDUCE_512(dv, divs);
    const float divloss = divs * (1.f / 262144.f);

    float lp = lossPart[t];
    float prim; BLOCK_REDUCE_512(lp, prim);
    prim *= 1.f / 8388608.f;

    if (t == 0) {
        out_scal[0] = prim + 0.5f * ereg + 0.5f * divloss;
        out_scal[1] = exp2f(Hbits);
    }
}

// ---------------- launch -----------------------------------------------------
extern "C" void kernel_launch(void* const* d_in, const int* in_sizes, int n_in,
                              void* d_out, int out_size, void* d_ws, size_t ws_size,
                              hipStream_t stream)
{
    const float* inputs = (const float*)d_in[0];
    const float* gamma  = (const float*)d_in[1];
    const float* beta   = (const float*)d_in[2];
    const float* C      = (const float*)d_in[3];   // (D,K)
    const float* d_w    = (const float*)d_in[4];   // (D,D)
    const float* d_b    = (const float*)d_in[5];   // (D,)

    float* out = (float*)d_out;
    float* Z = out;                                 // M*D slot (Z, later Zq)
    float* P = out + (size_t)M_ * D_;               // M*K slot (P_sol -> P_proj)
    float* out_scal = P + (size_t)M_ * K_;          // loss, perplexity

    float* w = (float*)d_ws;
    float* Smat = w;     w += D_ * D_;
    float* Xa   = w;     w += D_ * D_;
    float* Xb   = w;     w += D_ * D_;
    float* Tb   = w;     w += D_ * D_;
    float* Ut   = w;     w += K_ * D_;              // C^T Sinv  (512x256)
    float* Ainv = w;     w += K_ * K_;
    float* Ct   = w;     w += K_ * D_;
    float* cn2  = w;     w += K_;
    float* zn2  = w;     w += M_;
    float* part = w;     w += 256 * K_;
    float* lossPart = w; w += 512;
    float* divPart  = w; w += 64;
    float* PV   = w;     w += M_ * 4;
    float* PB   = w;     w += M_ * 4;
    int* PI     = (int*)w; w += M_ * 4;
    int* rlist  = (int*)w; w += M_;
    int* rcount = (int*)w; w += 16;
    int* assign = (int*)w;

    hipMemsetAsync(rcount, 0, sizeof(int), stream);

    // 1. Z = LN(inputs @ d_w + d_b), zn2    (f32, argmin-critical)
    dense_ln_kernel<<<M_/64, 256, 0, stream>>>(inputs, d_w, d_b, gamma, beta, Z, zn2);
    // 2. C^T and column norms
    transpose_ct<<<(K_ * D_) / 256, 256, 0, stream>>>(C, Ct);
    cn2_kernel<<<K_ / 256, 256, 0, stream>>>(C, cn2);
    // 3. S = C C^T + I
    small_gemm<1, 3><<<dim3(D_/64, D_/64), 256, 0, stream>>>(Ct, Ct, nullptr, Smat, D_, D_, K_, nullptr, nullptr);
    // 4. NS init
    scal_init_kernel<<<1, 256, 0, stream>>>(Smat, Xa);
    // 5. Newton-Schulz x6: X <- 2X - X S X
    float* Xc = Xa; float* Xn = Xb;
    for (int it = 0; it < 6; ++it) {
        small_gemm<0, 0><<<dim3(D_/64, D_/64), 256, 0, stream>>>(Smat, Xc, nullptr, Tb, D_, D_, D_, nullptr, nullptr);
        small_gemm<0, 1><<<dim3(D_/64, D_/64), 256, 0, stream>>>(Xc, Tb, Xc, Xn, D_, D_, D_, nullptr, nullptr);
        float* tmp = Xc; Xc = Xn; Xn = tmp;
    }
    // 6. Ut = C^T Sinv ; Ainv = I - Ut C ; diversity partials from C^T C
    small_gemm<1, 0><<<dim3(D_/64, K_/64), 256, 0, stream>>>(C, Xc, nullptr, Ut, K_, D_, D_, nullptr, nullptr);
    small_gemm<0, 2><<<dim3(K_/64, K_/64), 256, 0, stream>>>(Ut, C, nullptr, Ainv, K_, K_, D_, nullptr, nullptr);
    small_gemm<1, 4><<<dim3(K_/64, K_/64), 256, 0, stream>>>(C, C, nullptr, nullptr, K_, K_, D_, cn2, divPart);
    // 7. approx dists (split-bf16 MFMA) + top-2 -> provisional assign + repair
    score_mfma_argmin<<<dim3(K_/128, M_/128), 256, 0, stream>>>(Z, Ct, cn2, zn2, PV, PB, PI);
    argmin_reduce4<<<M_/256, 256, 0, stream>>>(PV, PB, PI, assign, rlist, rcount);
    repair_kernel<<<256, 256, 0, stream>>>(Z, Ct, cn2, zn2, rlist, rcount, assign);
    // 8. P_sol^T = Z @ Ut^T + Ainv[assign,:]   (split-bf16 MFMA)
    mfma_gemm<2><<<dim3(K_/128, M_/128), 256, 0, stream>>>(
        Z, Ut, P, D_, K_, Ainv, assign, nullptr, nullptr);
    // 9. simplex projection in place
    project_kernel<<<M_/4, 256, 0, stream>>>(P);
    // 10. column partial sums
    colsum_kernel<<<256, 512, 0, stream>>>(P, part);
    // 11. Zq = P @ C^T (split-bf16 MFMA; B^T = C), loss partials
    mfma_gemm<3><<<dim3(D_/128, M_/128), 256, 0, stream>>>(
        P, C, Z, K_, D_, nullptr, nullptr, Z, lossPart);
    // 12. scalars
    finalize_kernel<<<1, 512, 0, stream>>>(part, divPart, lossPart, out_scal);

    (void)in_sizes; (void)n_in; (void)out_size; (void)ws_size;
}